// Round 7
// baseline (112.099 us; speedup 1.0000x reference)
//
#include <hip/hip_runtime.h>
#include <hip/hip_bf16.h>
#include <stdint.h>

typedef __attribute__((ext_vector_type(8))) short bf16x8;
typedef __attribute__((ext_vector_type(4))) float f32x4;

#define DIN 1024
#define NROWS 8192

__device__ __forceinline__ unsigned short f2bf(float f) {
    union { float f; unsigned u; } v; v.f = f;
    unsigned r = v.u + 0x7FFFu + ((v.u >> 16) & 1u);  // RNE
    return (unsigned short)(r >> 16);
}

__device__ __forceinline__ int fswz(int r) { return (r ^ (r >> 2)) & 3; }

// physical byte offset of logical element `col` (col multiple of 4) in row R of a
// row-major [*, 1024] bf16 array stored with 16B-chunk XOR swizzle within 64B groups
__device__ __forceinline__ size_t swz_byte(int R, int col) {
    return ((size_t)R * DIN + (col & ~31)) * 2 + (size_t)((((col >> 3) & 3) ^ fswz(R)) << 4) + (size_t)((col & 7) * 2);
}

__device__ __forceinline__ void gload_lds16(const void* g, void* l) {
    __builtin_amdgcn_global_load_lds(
        (const __attribute__((address_space(1))) unsigned*)g,
        (__attribute__((address_space(3))) unsigned*)l, 16, 0, 0);
}

// ---- Kernel A: vab/vag/c + cast Wab,Wag -> bf16 (pre-swizzled) ----
__global__ __launch_bounds__(256) void prep_kernel(const float* __restrict__ Wab,
                                                   const float* __restrict__ Wag,
                                                   const float* __restrict__ bab,
                                                   const float* __restrict__ bag,
                                                   float* __restrict__ ws_f,
                                                   unsigned short* __restrict__ Whab,
                                                   unsigned short* __restrict__ Whag) {
    int b = blockIdx.x;
    int wave = threadIdx.x >> 6, lane = threadIdx.x & 63;
    if (b == 256) {
        if (wave == 0) {
            float acc = 0.f;
            for (int j = lane; j < DIN; j += 64) acc += bab[j] * bag[j];
            for (int off = 32; off; off >>= 1) acc += __shfl_xor(acc, off);
            if (lane == 0) ws_f[2048] = acc;
        }
        return;
    }
    int r = b * 4 + wave;
    int fr = fswz(r);
    {
        const float* wrow = Wab + (size_t)r * DIN;
        char* hrow = (char*)Whab + (size_t)r * DIN * 2;
        float acc = 0.f;
#pragma unroll
        for (int it = 0; it < 4; ++it) {
            int col = it * 256 + lane * 4;
            float4 w = *reinterpret_cast<const float4*>(wrow + col);
            float4 bv = *reinterpret_cast<const float4*>(bag + col);
            acc += w.x * bv.x + w.y * bv.y + w.z * bv.z + w.w * bv.w;
            ushort4 h; h.x = f2bf(w.x); h.y = f2bf(w.y); h.z = f2bf(w.z); h.w = f2bf(w.w);
            *reinterpret_cast<ushort4*>(hrow + (col & ~31) * 2 + ((((col >> 3) & 3) ^ fr) << 4) + (col & 7) * 2) = h;
        }
        for (int off = 32; off; off >>= 1) acc += __shfl_xor(acc, off);
        if (lane == 0) ws_f[r] = acc;          // vab
    }
    {
        const float* wrow = Wag + (size_t)r * DIN;
        char* hrow = (char*)Whag + (size_t)r * DIN * 2;
        float acc = 0.f;
#pragma unroll
        for (int it = 0; it < 4; ++it) {
            int col = it * 256 + lane * 4;
            float4 w = *reinterpret_cast<const float4*>(wrow + col);
            float4 bv = *reinterpret_cast<const float4*>(bab + col);
            acc += w.x * bv.x + w.y * bv.y + w.z * bv.z + w.w * bv.w;
            ushort4 h; h.x = f2bf(w.x); h.y = f2bf(w.y); h.z = f2bf(w.z); h.w = f2bf(w.w);
            *reinterpret_cast<ushort4*>(hrow + (col & ~31) * 2 + ((((col >> 3) & 3) ^ fr) << 4) + (col & 7) * 2) = h;
        }
        for (int off = 32; off; off >>= 1) acc += __shfl_xor(acc, off);
        if (lane == 0) ws_f[1024 + r] = acc;   // vag
    }
}

// ---- Kernel B: Mt[l,k] = Wag[l,:].Wab[k,:] (bf16, swizzled out); 64x64 tile,
//      8 waves = 2 K-split groups x 4, gload_lds 2-phase pipeline ----
__global__ __launch_bounds__(512) void mt_kernel(const unsigned short* __restrict__ Whag,
                                                 const unsigned short* __restrict__ Whab,
                                                 unsigned short* __restrict__ Mt) {
    __shared__ unsigned short sm[2][2][2][2048];   // [grp][buf][op][64*32] = 32 KB
    int tid = threadIdx.x;
    int wave = tid >> 6, grp = wave >> 2, w4 = wave & 3;
    int lane = tid & 63, kg = lane >> 4, cl = lane & 15;
    int wr = w4 >> 1, wc = w4 & 1;
    int br = blockIdx.x >> 4, bc = blockIdx.x & 15;
    int u = tid & 255, urow = u >> 2, uchunk = u & 3;

    const char* Abase = (const char*)Whag + ((size_t)(br * 64 + urow) * DIN + grp * 512) * 2 + uchunk * 16;
    const char* Bbase = (const char*)Whab + ((size_t)(bc * 64 + urow) * DIN + grp * 512) * 2 + uchunk * 16;

    int offA[2], offB[2];
#pragma unroll
    for (int m = 0; m < 2; ++m) { int row = wr * 32 + m * 16 + cl; offA[m] = row * 32 + ((kg ^ fswz(row)) << 3); }
#pragma unroll
    for (int n = 0; n < 2; ++n) { int row = wc * 32 + n * 16 + cl; offB[n] = row * 32 + ((kg ^ fswz(row)) << 3); }

    f32x4 acc[2][2] = {};
    gload_lds16(Abase, &sm[grp][0][0][u * 8]);
    gload_lds16(Bbase, &sm[grp][0][1][u * 8]);
    __syncthreads();
    for (int t = 0; t < 16; ++t) {
        int p = t & 1;
        if (t < 15) {
            gload_lds16(Abase + (t + 1) * 64, &sm[grp][p ^ 1][0][u * 8]);
            gload_lds16(Bbase + (t + 1) * 64, &sm[grp][p ^ 1][1][u * 8]);
        }
        bf16x8 af[2], bfr[2];
#pragma unroll
        for (int m = 0; m < 2; ++m) af[m] = *reinterpret_cast<const bf16x8*>(&sm[grp][p][0][offA[m]]);
#pragma unroll
        for (int n = 0; n < 2; ++n) bfr[n] = *reinterpret_cast<const bf16x8*>(&sm[grp][p][1][offB[n]]);
#pragma unroll
        for (int m = 0; m < 2; ++m)
#pragma unroll
            for (int n = 0; n < 2; ++n)
                acc[m][n] = __builtin_amdgcn_mfma_f32_16x16x32_bf16(af[m], bfr[n], acc[m][n], 0, 0, 0);
        __syncthreads();
    }
    // cross-group K reduction via LDS (aliased over staging buffers)
    float* red = (float*)sm;   // [64][68] padded
    if (grp == 1) {
#pragma unroll
        for (int m = 0; m < 2; ++m)
#pragma unroll
            for (int n = 0; n < 2; ++n)
#pragma unroll
                for (int j = 0; j < 4; ++j)
                    red[(wr * 32 + m * 16 + kg * 4 + j) * 68 + wc * 32 + n * 16 + cl] = acc[m][n][j];
    }
    __syncthreads();
    if (grp == 0) {
#pragma unroll
        for (int m = 0; m < 2; ++m)
#pragma unroll
            for (int n = 0; n < 2; ++n)
#pragma unroll
                for (int j = 0; j < 4; ++j) {
                    int rl = wr * 32 + m * 16 + kg * 4 + j, cll = wc * 32 + n * 16 + cl;
                    float v = acc[m][n][j] + red[rl * 68 + cll];
                    int R = br * 64 + rl, C = bc * 64 + cll;
                    *(unsigned short*)((char*)Mt + swz_byte(R, C & ~3) + (C & 3) * 2) = f2bf(v);
                }
    }
}

// ---- Kernel C (mega): heterogeneous roles on co-resident blocks.
//  blocks [0,256):    stream role — h2 + Term2 + c (BW-bound, fills gemm stalls)
//  blocks [256,1280): gemm role — P = gAB@Mt^T, Term1+Term3 epilogue (stall-bound)
//  5 blocks/CU (LDS 32KB x 5 = 160KB): each CU hosts ~1 stream + ~4 gemm blocks. ----
__global__ __launch_bounds__(256, 5) void mega_kernel(const float* __restrict__ gAB,
                                                      const float* __restrict__ gAG,
                                                      const float* __restrict__ sAB,
                                                      const float* __restrict__ sAG,
                                                      const unsigned short* __restrict__ Mt,
                                                      const float* __restrict__ ws_f,
                                                      float* __restrict__ out) {
    __shared__ unsigned short lds_a[2][128 * 32];   // 8 KB per buffer
    __shared__ unsigned short lds_b[2][128 * 32];
    int b = blockIdx.x;
    int tid = threadIdx.x, wave = tid >> 6, lane = tid & 63;

    if (b < 256) {
        // ---------------- stream role ----------------
        float cbias = ws_f[2048];
        float4 vb[4];
#pragma unroll
        for (int cc = 0; cc < 4; ++cc)
            vb[cc] = *reinterpret_cast<const float4*>(ws_f + cc * 256 + lane * 4);  // vab
        int row_base = b * 32 + wave * 8;
        for (int rr = 0; rr < 8; ++rr) {
            int row = row_base + rr;
            const float* ga = gAB + (size_t)row * DIN;
            const float* sa = sAB + (size_t)row * DIN;
            const float* sg = sAG + (size_t)row * DIN;
            float acc = 0.f;
#pragma unroll
            for (int cc = 0; cc < 4; ++cc) {
                int col = cc * 256 + lane * 4;
                float4 a = *reinterpret_cast<const float4*>(ga + col);
                float4 x = *reinterpret_cast<const float4*>(sa + col);
                float4 y = *reinterpret_cast<const float4*>(sg + col);
                acc += x.x * y.x + x.y * y.y + x.z * y.z + x.w * y.w;
                acc += a.x * vb[cc].x + a.y * vb[cc].y + a.z * vb[cc].z + a.w * vb[cc].w;
            }
#pragma unroll
            for (int off = 32; off; off >>= 1) acc += __shfl_xor(acc, off);
            if (lane == 0) atomicAdd(out + row, 0.5f * (acc + cbias));
        }
        return;
    }

    // ---------------- gemm role ----------------
    constexpr int KSPLIT = 2;
    constexpr int KLEN = DIN / KSPLIT;    // 512
    constexpr int NSTEP = KLEN / 32;      // 16
    int g = b - 256;
    int x = g & 7, s = g >> 3;            // s in [0,128)
    int rblk = x + 8 * (s & 7);           // 0..63
    int u2 = s >> 3;                      // 0..15
    int ks = u2 & (KSPLIT - 1);
    int cblk = u2 / KSPLIT;               // 0..7
    int wr = wave >> 1, wc = wave & 1;
    int kg = lane >> 4, cl = lane & 15;
    int row0 = rblk * 128, col0 = cblk * 128;

    int offA[4], offB[4];
#pragma unroll
    for (int m = 0; m < 4; ++m) { int row = wr * 64 + m * 16 + cl; offA[m] = row * 32 + ((kg ^ fswz(row)) << 3); }
#pragma unroll
    for (int n = 0; n < 4; ++n) { int row = wc * 64 + n * 16 + cl; offB[n] = row * 32 + ((kg ^ fswz(row)) << 3); }

    size_t kofs = (size_t)(ks * KLEN);
    const char* Bb = (const char*)Mt + ((size_t)col0 * DIN + kofs) * 2;
    int u0 = tid, u1 = tid + 256;
    size_t b0 = (size_t)(u0 >> 2) * (DIN * 2) + (u0 & 3) * 16;
    size_t b1 = (size_t)(u1 >> 2) * (DIN * 2) + (u1 & 3) * 16;
    const float* Abase = gAB + (size_t)row0 * DIN + kofs;

    f32x4 acc[4][4] = {};
    float4 ra[4];

    // prologue: stage t=0 into buf 0
    gload_lds16(Bb + b0, (char*)&lds_b[0][0] + u0 * 16);
    gload_lds16(Bb + b1, (char*)&lds_b[0][0] + u1 * 16);
#pragma unroll
    for (int it = 0; it < 4; ++it) {
        int u = tid + it * 256;
        ra[it] = *reinterpret_cast<const float4*>(Abase + (size_t)(u >> 3) * DIN + (u & 7) * 4);
    }
#pragma unroll
    for (int it = 0; it < 4; ++it) {
        int u = tid + it * 256, row = u >> 3, c4 = u & 7;
        ushort4 h; h.x = f2bf(ra[it].x); h.y = f2bf(ra[it].y); h.z = f2bf(ra[it].z); h.w = f2bf(ra[it].w);
        *reinterpret_cast<ushort4*>((char*)&lds_a[0][0] + row * 64 + ((((c4 >> 1) ^ fswz(row))) << 4) + (c4 & 1) * 8) = h;
    }
    __syncthreads();

    for (int t = 0; t < NSTEP; ++t) {
        int p = t & 1;
        if (t < NSTEP - 1) {
            // prefetch t+1: A -> regs (written to LDS post-MFMA), B -> LDS direct
#pragma unroll
            for (int it = 0; it < 4; ++it) {
                int u = tid + it * 256;
                ra[it] = *reinterpret_cast<const float4*>(Abase + (size_t)(u >> 3) * DIN + (t + 1) * 32 + (u & 7) * 4);
            }
            gload_lds16(Bb + b0 + (t + 1) * 64, (char*)&lds_b[p ^ 1][0] + u0 * 16);
            gload_lds16(Bb + b1 + (t + 1) * 64, (char*)&lds_b[p ^ 1][0] + u1 * 16);
        }
        bf16x8 af[4], bfr[4];
#pragma unroll
        for (int m = 0; m < 4; ++m) af[m] = *reinterpret_cast<const bf16x8*>(&lds_a[p][offA[m]]);
#pragma unroll
        for (int n = 0; n < 4; ++n) bfr[n] = *reinterpret_cast<const bf16x8*>(&lds_b[p][offB[n]]);
#pragma unroll
        for (int m = 0; m < 4; ++m)
#pragma unroll
            for (int n = 0; n < 4; ++n)
                acc[m][n] = __builtin_amdgcn_mfma_f32_16x16x32_bf16(af[m], bfr[n], acc[m][n], 0, 0, 0);
        if (t < NSTEP - 1) {
#pragma unroll
            for (int it = 0; it < 4; ++it) {
                int u = tid + it * 256, row = u >> 3, c4 = u & 7;
                ushort4 h; h.x = f2bf(ra[it].x); h.y = f2bf(ra[it].y); h.z = f2bf(ra[it].z); h.w = f2bf(ra[it].w);
                *reinterpret_cast<ushort4*>((char*)&lds_a[p ^ 1][0] + row * 64 + ((((c4 >> 1) ^ fswz(row))) << 4) + (c4 & 1) * 8) = h;
            }
        }
        __syncthreads();
    }

    // epilogue: Term1 (all ks) + Term3 (ks==0 only); gAG kept fp32
    const float* vag = ws_f + 1024;
#pragma unroll
    for (int m = 0; m < 4; ++m)
#pragma unroll
        for (int j = 0; j < 4; ++j) {
            int row = row0 + wr * 64 + m * 16 + kg * 4 + j;
            const float* gr = gAG + (size_t)row * DIN;
            float t = 0.f;
#pragma unroll
            for (int n = 0; n < 4; ++n) {
                int col = col0 + wc * 64 + n * 16 + cl;
                float addv = (ks == 0) ? vag[col] : 0.f;
                t += gr[col] * (acc[m][n][j] + addv);
            }
            t += __shfl_xor(t, 1);
            t += __shfl_xor(t, 2);
            t += __shfl_xor(t, 4);
            t += __shfl_xor(t, 8);
            if (cl == 0) atomicAdd(out + row, 0.5f * t);
        }
}

extern "C" void kernel_launch(void* const* d_in, const int* in_sizes, int n_in,
                              void* d_out, int out_size, void* d_ws, size_t ws_size,
                              hipStream_t stream) {
    const float* gAB = (const float*)d_in[0];
    const float* gAG = (const float*)d_in[1];
    const float* Wab = (const float*)d_in[2];
    const float* Wag = (const float*)d_in[3];
    const float* bab = (const float*)d_in[4];
    const float* bag = (const float*)d_in[5];
    const float* sAB = (const float*)d_in[6];
    const float* sAG = (const float*)d_in[7];
    float* out = (float*)d_out;

    // ws layout: ws_f 16KB | Mt 2MB | Whag 2MB | Whab 2MB
    float* ws_f = (float*)d_ws;
    char* base = (char*)d_ws + 16384;
    unsigned short* Mt = (unsigned short*)base;
    unsigned short* Whag = (unsigned short*)(base + (size_t)2 * 1024 * 1024);
    unsigned short* Whab = (unsigned short*)(base + (size_t)4 * 1024 * 1024);

    hipMemsetAsync(d_out, 0, (size_t)out_size * sizeof(float), stream);
    prep_kernel<<<257, 256, 0, stream>>>(Wab, Wag, bab, bag, ws_f, Whab, Whag);
    mt_kernel<<<256, 512, 0, stream>>>(Whag, Whab, Mt);
    mega_kernel<<<1280, 256, 0, stream>>>(gAB, gAG, sAB, sAG, Mt, ws_f, out);
}

// Round 8
// 67.147 us; speedup vs baseline: 1.6695x; 1.6695x over previous
//
#include <hip/hip_runtime.h>
#include <hip/hip_bf16.h>
#include <stdint.h>

typedef __attribute__((ext_vector_type(8))) short bf16x8;
typedef __attribute__((ext_vector_type(4))) float f32x4;

#define DIN 1024
#define NROWS 8192

__device__ __forceinline__ unsigned short f2bf(float f) {
    union { float f; unsigned u; } v; v.f = f;
    unsigned r = v.u + 0x7FFFu + ((v.u >> 16) & 1u);  // RNE
    return (unsigned short)(r >> 16);
}

__device__ __forceinline__ int fswz(int r) { return (r ^ (r >> 2)) & 3; }

// physical byte offset of logical element `col` (col multiple of 4) in row R of a
// row-major [*, 1024] bf16 array stored with 16B-chunk XOR swizzle within 64B groups
__device__ __forceinline__ size_t swz_byte(int R, int col) {
    return ((size_t)R * DIN + (col & ~31)) * 2 + (size_t)((((col >> 3) & 3) ^ fswz(R)) << 4) + (size_t)((col & 7) * 2);
}

__device__ __forceinline__ void gload_lds16(const void* g, void* l) {
    __builtin_amdgcn_global_load_lds(
        (const __attribute__((address_space(1))) unsigned*)g,
        (__attribute__((address_space(3))) unsigned*)l, 16, 0, 0);
}

// ---- Kernel A: vab/vag/c + cast Wab,Wag -> bf16 (pre-swizzled) ----
__global__ __launch_bounds__(256) void prep_kernel(const float* __restrict__ Wab,
                                                   const float* __restrict__ Wag,
                                                   const float* __restrict__ bab,
                                                   const float* __restrict__ bag,
                                                   float* __restrict__ ws_f,
                                                   unsigned short* __restrict__ Whab,
                                                   unsigned short* __restrict__ Whag) {
    int b = blockIdx.x;
    int wave = threadIdx.x >> 6, lane = threadIdx.x & 63;
    if (b == 256) {
        if (wave == 0) {
            float acc = 0.f;
            for (int j = lane; j < DIN; j += 64) acc += bab[j] * bag[j];
            for (int off = 32; off; off >>= 1) acc += __shfl_xor(acc, off);
            if (lane == 0) ws_f[2048] = acc;
        }
        return;
    }
    int r = b * 4 + wave;
    int fr = fswz(r);
    {
        const float* wrow = Wab + (size_t)r * DIN;
        char* hrow = (char*)Whab + (size_t)r * DIN * 2;
        float acc = 0.f;
#pragma unroll
        for (int it = 0; it < 4; ++it) {
            int col = it * 256 + lane * 4;
            float4 w = *reinterpret_cast<const float4*>(wrow + col);
            float4 bv = *reinterpret_cast<const float4*>(bag + col);
            acc += w.x * bv.x + w.y * bv.y + w.z * bv.z + w.w * bv.w;
            ushort4 h; h.x = f2bf(w.x); h.y = f2bf(w.y); h.z = f2bf(w.z); h.w = f2bf(w.w);
            *reinterpret_cast<ushort4*>(hrow + (col & ~31) * 2 + ((((col >> 3) & 3) ^ fr) << 4) + (col & 7) * 2) = h;
        }
        for (int off = 32; off; off >>= 1) acc += __shfl_xor(acc, off);
        if (lane == 0) ws_f[r] = acc;          // vab
    }
    {
        const float* wrow = Wag + (size_t)r * DIN;
        char* hrow = (char*)Whag + (size_t)r * DIN * 2;
        float acc = 0.f;
#pragma unroll
        for (int it = 0; it < 4; ++it) {
            int col = it * 256 + lane * 4;
            float4 w = *reinterpret_cast<const float4*>(wrow + col);
            float4 bv = *reinterpret_cast<const float4*>(bab + col);
            acc += w.x * bv.x + w.y * bv.y + w.z * bv.z + w.w * bv.w;
            ushort4 h; h.x = f2bf(w.x); h.y = f2bf(w.y); h.z = f2bf(w.z); h.w = f2bf(w.w);
            *reinterpret_cast<ushort4*>(hrow + (col & ~31) * 2 + ((((col >> 3) & 3) ^ fr) << 4) + (col & 7) * 2) = h;
        }
        for (int off = 32; off; off >>= 1) acc += __shfl_xor(acc, off);
        if (lane == 0) ws_f[1024 + r] = acc;   // vag
    }
}

// ---- Kernel B: Mt[l,k] = Wag[l,:].Wab[k,:] (bf16, swizzled out); 64x64 tile,
//      8 waves = 2 K-split groups x 4; stage-AFTER-barrier pipeline ----
__global__ __launch_bounds__(512) void mt_kernel(const unsigned short* __restrict__ Whag,
                                                 const unsigned short* __restrict__ Whab,
                                                 unsigned short* __restrict__ Mt) {
    __shared__ unsigned short sm[2][2][2][2048];   // [grp][buf][op][64*32] = 32 KB
    int tid = threadIdx.x;
    int wave = tid >> 6, grp = wave >> 2, w4 = wave & 3;
    int lane = tid & 63, kg = lane >> 4, cl = lane & 15;
    int wr = w4 >> 1, wc = w4 & 1;
    int br = blockIdx.x >> 4, bc = blockIdx.x & 15;
    int u = tid & 255, urow = u >> 2, uchunk = u & 3;

    const char* Abase = (const char*)Whag + ((size_t)(br * 64 + urow) * DIN + grp * 512) * 2 + uchunk * 16;
    const char* Bbase = (const char*)Whab + ((size_t)(bc * 64 + urow) * DIN + grp * 512) * 2 + uchunk * 16;

    int offA[2], offB[2];
#pragma unroll
    for (int m = 0; m < 2; ++m) { int row = wr * 32 + m * 16 + cl; offA[m] = row * 32 + ((kg ^ fswz(row)) << 3); }
#pragma unroll
    for (int n = 0; n < 2; ++n) { int row = wc * 32 + n * 16 + cl; offB[n] = row * 32 + ((kg ^ fswz(row)) << 3); }

    f32x4 acc[2][2] = {};
    gload_lds16(Abase, &sm[grp][0][0][u * 8]);
    gload_lds16(Bbase, &sm[grp][0][1][u * 8]);
    for (int t = 0; t < 16; ++t) {
        int p = t & 1;
        __syncthreads();                       // drains only tile-t loads (t+1 not yet staged)
        if (t < 15) {
            gload_lds16(Abase + (t + 1) * 64, &sm[grp][p ^ 1][0][u * 8]);
            gload_lds16(Bbase + (t + 1) * 64, &sm[grp][p ^ 1][1][u * 8]);
        }
        bf16x8 af[2], bfr[2];
#pragma unroll
        for (int m = 0; m < 2; ++m) af[m] = *reinterpret_cast<const bf16x8*>(&sm[grp][p][0][offA[m]]);
#pragma unroll
        for (int n = 0; n < 2; ++n) bfr[n] = *reinterpret_cast<const bf16x8*>(&sm[grp][p][1][offB[n]]);
        __builtin_amdgcn_s_setprio(1);
#pragma unroll
        for (int m = 0; m < 2; ++m)
#pragma unroll
            for (int n = 0; n < 2; ++n)
                acc[m][n] = __builtin_amdgcn_mfma_f32_16x16x32_bf16(af[m], bfr[n], acc[m][n], 0, 0, 0);
        __builtin_amdgcn_s_setprio(0);
    }
    __syncthreads();
    // cross-group K reduction via LDS (aliased over staging buffers)
    float* red = (float*)sm;   // [64][68] padded
    if (grp == 1) {
#pragma unroll
        for (int m = 0; m < 2; ++m)
#pragma unroll
            for (int n = 0; n < 2; ++n)
#pragma unroll
                for (int j = 0; j < 4; ++j)
                    red[(wr * 32 + m * 16 + kg * 4 + j) * 68 + wc * 32 + n * 16 + cl] = acc[m][n][j];
    }
    __syncthreads();
    if (grp == 0) {
#pragma unroll
        for (int m = 0; m < 2; ++m)
#pragma unroll
            for (int n = 0; n < 2; ++n)
#pragma unroll
                for (int j = 0; j < 4; ++j) {
                    int rl = wr * 32 + m * 16 + kg * 4 + j, cll = wc * 32 + n * 16 + cl;
                    float v = acc[m][n][j] + red[rl * 68 + cll];
                    int R = br * 64 + rl, C = bc * 64 + cll;
                    *(unsigned short*)((char*)Mt + swz_byte(R, C & ~3) + (C & 3) * 2) = f2bf(v);
                }
    }
}

// ---- Kernel C: streaming — h2 + Term2 + c, cast gAB -> bf16 (swizzled) ----
__global__ __launch_bounds__(256) void stream_kernel(const float* __restrict__ gAB,
                                                     const float* __restrict__ sAB,
                                                     const float* __restrict__ sAG,
                                                     const float* __restrict__ ws_f,
                                                     unsigned short* __restrict__ gABh,
                                                     float* __restrict__ out,
                                                     int writecast) {
    int wave = threadIdx.x >> 6, lane = threadIdx.x & 63;
    int row = blockIdx.x * 4 + wave;
    const float* ga = gAB + (size_t)row * DIN;
    const float* sa = sAB + (size_t)row * DIN;
    const float* sg = sAG + (size_t)row * DIN;
    char* gh = (char*)gABh + (size_t)row * DIN * 2;
    int fr = fswz(row);
    float acc = 0.f;
#pragma unroll
    for (int cc = 0; cc < 4; ++cc) {
        int col = cc * 256 + lane * 4;
        float4 a = *reinterpret_cast<const float4*>(ga + col);
        float4 x = *reinterpret_cast<const float4*>(sa + col);
        float4 y = *reinterpret_cast<const float4*>(sg + col);
        float4 v = *reinterpret_cast<const float4*>(ws_f + col);   // vab
        acc += x.x * y.x + x.y * y.y + x.z * y.z + x.w * y.w;
        acc += a.x * v.x + a.y * v.y + a.z * v.z + a.w * v.w;
        if (writecast) {
            ushort4 h; h.x = f2bf(a.x); h.y = f2bf(a.y); h.z = f2bf(a.z); h.w = f2bf(a.w);
            *reinterpret_cast<ushort4*>(gh + (col & ~31) * 2 + ((((col >> 3) & 3) ^ fr) << 4) + (col & 7) * 2) = h;
        }
    }
#pragma unroll
    for (int off = 32; off; off >>= 1) acc += __shfl_xor(acc, off);
    if (lane == 0) out[row] = 0.5f * (acc + ws_f[2048]);
}

// ---- Kernel D: P = gAB @ Mt^T fused Term1+Term3; stage-AFTER-barrier pipeline ----
template <int PRECAST, int KSPLIT>
__global__ __launch_bounds__(256, 4) void gemm_kernel(const float* __restrict__ gAB,
                                                      const unsigned short* __restrict__ gABh,
                                                      const float* __restrict__ gAG,
                                                      const unsigned short* __restrict__ Mt,
                                                      const float* __restrict__ ws_f,
                                                      float* __restrict__ out) {
    __shared__ unsigned short lds_a[2][128 * 32];
    __shared__ unsigned short lds_b[2][128 * 32];
    constexpr int KLEN = DIN / KSPLIT;
    constexpr int NSTEP = KLEN / 32;
    int b = blockIdx.x;
    // XCD map: x = XCD id; within an XCD, rblk cycles fastest, then ks, then cblk
    int x = b & 7, s = b >> 3;
    int rblk = x + 8 * (s & 7);
    int u2 = s >> 3;                       // 0..(8*KSPLIT-1)
    int ks = u2 & (KSPLIT - 1);
    int cblk = u2 / KSPLIT;
    int tid = threadIdx.x, wave = tid >> 6, lane = tid & 63;
    int wr = wave >> 1, wc = wave & 1;
    int kg = lane >> 4, cl = lane & 15;
    int row0 = rblk * 128, col0 = cblk * 128;

    int offA[4], offB[4];
#pragma unroll
    for (int m = 0; m < 4; ++m) { int row = wr * 64 + m * 16 + cl; offA[m] = row * 32 + ((kg ^ fswz(row)) << 3); }
#pragma unroll
    for (int n = 0; n < 4; ++n) { int row = wc * 64 + n * 16 + cl; offB[n] = row * 32 + ((kg ^ fswz(row)) << 3); }

    size_t kofs = (size_t)(ks * KLEN) * 2;
    const char* Ab = (const char*)gABh + (size_t)row0 * DIN * 2 + kofs;
    const char* Bb = (const char*)Mt + (size_t)col0 * DIN * 2 + kofs;
    int u0 = tid, u1 = tid + 256;
    size_t a0 = (size_t)(u0 >> 2) * (DIN * 2) + (u0 & 3) * 16;
    size_t a1 = (size_t)(u1 >> 2) * (DIN * 2) + (u1 & 3) * 16;

    f32x4 acc[4][4] = {};
    float4 ra[4];
    if (PRECAST) {
        // prologue: stage tile 0 into buf 0
        gload_lds16(Ab + a0, (char*)&lds_a[0][0] + u0 * 16);
        gload_lds16(Ab + a1, (char*)&lds_a[0][0] + u1 * 16);
        gload_lds16(Bb + a0, (char*)&lds_b[0][0] + u0 * 16);
        gload_lds16(Bb + a1, (char*)&lds_b[0][0] + u1 * 16);

        for (int t = 0; t < NSTEP; ++t) {
            int p = t & 1;
            // barrier FIRST: its vmcnt(0) drain waits only tile-t loads (t+1 not staged yet).
            __syncthreads();
            if (t < NSTEP - 1) {
                // stage t+1 AFTER the barrier: loads fly during this step's ds_read+MFMA
                gload_lds16(Ab + a0 + (t + 1) * 64, (char*)&lds_a[p ^ 1][0] + u0 * 16);
                gload_lds16(Ab + a1 + (t + 1) * 64, (char*)&lds_a[p ^ 1][0] + u1 * 16);
                gload_lds16(Bb + a0 + (t + 1) * 64, (char*)&lds_b[p ^ 1][0] + u0 * 16);
                gload_lds16(Bb + a1 + (t + 1) * 64, (char*)&lds_b[p ^ 1][0] + u1 * 16);
            }
            bf16x8 af[4], bfr[4];
#pragma unroll
            for (int m = 0; m < 4; ++m) af[m] = *reinterpret_cast<const bf16x8*>(&lds_a[p][offA[m]]);
#pragma unroll
            for (int n = 0; n < 4; ++n) bfr[n] = *reinterpret_cast<const bf16x8*>(&lds_b[p][offB[n]]);
            __builtin_amdgcn_s_setprio(1);
#pragma unroll
            for (int m = 0; m < 4; ++m)
#pragma unroll
                for (int n = 0; n < 4; ++n)
                    acc[m][n] = __builtin_amdgcn_mfma_f32_16x16x32_bf16(af[m], bfr[n], acc[m][n], 0, 0, 0);
            __builtin_amdgcn_s_setprio(0);
        }
    } else {
        // fallback (small ws): fp32 reg-stage + convert, classic structure
#pragma unroll
        for (int it = 0; it < 4; ++it) {
            int u = tid + it * 256;
            ra[it] = *reinterpret_cast<const float4*>(gAB + (size_t)(row0 + (u >> 3)) * DIN + ks * KLEN + (u & 7) * 4);
        }
#pragma unroll
        for (int it = 0; it < 4; ++it) {
            int u = tid + it * 256, row = u >> 3, c4 = u & 7;
            ushort4 h; h.x = f2bf(ra[it].x); h.y = f2bf(ra[it].y); h.z = f2bf(ra[it].z); h.w = f2bf(ra[it].w);
            *reinterpret_cast<ushort4*>((char*)&lds_a[0][0] + row * 64 + ((((c4 >> 1) ^ fswz(row))) << 4) + (c4 & 1) * 8) = h;
        }
        gload_lds16(Bb + a0, (char*)&lds_b[0][0] + u0 * 16);
        gload_lds16(Bb + a1, (char*)&lds_b[0][0] + u1 * 16);
        for (int t = 0; t < NSTEP; ++t) {
            int p = t & 1;
            __syncthreads();
            if (t < NSTEP - 1) {
#pragma unroll
                for (int it = 0; it < 4; ++it) {
                    int u = tid + it * 256;
                    ra[it] = *reinterpret_cast<const float4*>(gAB + (size_t)(row0 + (u >> 3)) * DIN + ks * KLEN + (t + 1) * 32 + (u & 7) * 4);
                }
                gload_lds16(Bb + a0 + (t + 1) * 64, (char*)&lds_b[p ^ 1][0] + u0 * 16);
                gload_lds16(Bb + a1 + (t + 1) * 64, (char*)&lds_b[p ^ 1][0] + u1 * 16);
            }
            bf16x8 af[4], bfr[4];
#pragma unroll
            for (int m = 0; m < 4; ++m) af[m] = *reinterpret_cast<const bf16x8*>(&lds_a[p][offA[m]]);
#pragma unroll
            for (int n = 0; n < 4; ++n) bfr[n] = *reinterpret_cast<const bf16x8*>(&lds_b[p][offB[n]]);
#pragma unroll
            for (int m = 0; m < 4; ++m)
#pragma unroll
                for (int n = 0; n < 4; ++n)
                    acc[m][n] = __builtin_amdgcn_mfma_f32_16x16x32_bf16(af[m], bfr[n], acc[m][n], 0, 0, 0);
            if (t < NSTEP - 1) {
#pragma unroll
                for (int it = 0; it < 4; ++it) {
                    int u = tid + it * 256, row = u >> 3, c4 = u & 7;
                    ushort4 h; h.x = f2bf(ra[it].x); h.y = f2bf(ra[it].y); h.z = f2bf(ra[it].z); h.w = f2bf(ra[it].w);
                    *reinterpret_cast<ushort4*>((char*)&lds_a[p ^ 1][0] + row * 64 + ((((c4 >> 1) ^ fswz(row))) << 4) + (c4 & 1) * 8) = h;
                }
            }
        }
    }

    // epilogue: Term1 (all ks) + Term3 (ks==0 only); gAG kept fp32
    const float* vag = ws_f + 1024;
#pragma unroll
    for (int m = 0; m < 4; ++m)
#pragma unroll
        for (int j = 0; j < 4; ++j) {
            int row = row0 + wr * 64 + m * 16 + kg * 4 + j;
            const float* gr = gAG + (size_t)row * DIN;
            float t = 0.f;
#pragma unroll
            for (int n = 0; n < 4; ++n) {
                int col = col0 + wc * 64 + n * 16 + cl;
                float addv = (ks == 0) ? vag[col] : 0.f;
                t += gr[col] * (acc[m][n][j] + addv);
            }
            t += __shfl_xor(t, 1);
            t += __shfl_xor(t, 2);
            t += __shfl_xor(t, 4);
            t += __shfl_xor(t, 8);
            if (cl == 0) atomicAdd(out + row, 0.5f * t);
        }
}

extern "C" void kernel_launch(void* const* d_in, const int* in_sizes, int n_in,
                              void* d_out, int out_size, void* d_ws, size_t ws_size,
                              hipStream_t stream) {
    const float* gAB = (const float*)d_in[0];
    const float* gAG = (const float*)d_in[1];
    const float* Wab = (const float*)d_in[2];
    const float* Wag = (const float*)d_in[3];
    const float* bab = (const float*)d_in[4];
    const float* bag = (const float*)d_in[5];
    const float* sAB = (const float*)d_in[6];
    const float* sAG = (const float*)d_in[7];
    float* out = (float*)d_out;

    // ws layout: ws_f 16KB | Mt 2MB | Whag 2MB | Whab 2MB | gABh 16MB
    float* ws_f = (float*)d_ws;
    char* base = (char*)d_ws + 16384;
    unsigned short* Mt = (unsigned short*)base;
    unsigned short* Whag = (unsigned short*)(base + (size_t)2 * 1024 * 1024);
    unsigned short* Whab = (unsigned short*)(base + (size_t)4 * 1024 * 1024);
    unsigned short* gABh = (unsigned short*)(base + (size_t)6 * 1024 * 1024);
    size_t need_full = 16384 + (size_t)22 * 1024 * 1024;
    int precast = (ws_size >= need_full) ? 1 : 0;

    prep_kernel<<<257, 256, 0, stream>>>(Wab, Wag, bab, bag, ws_f, Whab, Whag);
    mt_kernel<<<256, 512, 0, stream>>>(Whag, Whab, Mt);
    stream_kernel<<<2048, 256, 0, stream>>>(gAB, sAB, sAG, ws_f, gABh, out, precast);
    if (precast)
        gemm_kernel<1, 2><<<1024, 256, 0, stream>>>(gAB, gABh, gAG, Mt, ws_f, out);
    else
        gemm_kernel<0, 2><<<1024, 256, 0, stream>>>(gAB, gABh, gAG, Mt, ws_f, out);
}